// Round 1
// baseline (178.495 us; speedup 1.0000x reference)
//
#include <hip/hip_runtime.h>
#include <hip/hip_bf16.h>
#include <stdint.h>

#define NB 8
#define SS 2048
#define DIN 1024
#define DOUT 64
#define MTOT (NB*SS)
#define SCALE 0.02209708691207961f   // 1/sqrt(2048)

typedef short  short8 __attribute__((ext_vector_type(8)));
typedef float  f32x4  __attribute__((ext_vector_type(4)));
typedef unsigned short us4 __attribute__((ext_vector_type(4)));

// workspace layout (bytes)
#define WT_OFF 0                       // bf16 [3][64][1024] = 393216 B (q-scale folded)
#define FM_OFF 393216                  // float [16384]      = 65536 B
#define Q_OFF  524288                  // bf16 [16384][64]   = 2 MiB
#define K_OFF  (Q_OFF + MTOT*DOUT*2)
#define VT_OFF (K_OFF + MTOT*DOUT*2)   // bf16 [8][64][2048] (V transposed)

__device__ __forceinline__ short f2bf(float f) {
  __bf16 h = (__bf16)f;
  return __builtin_bit_cast(short, h);
}

// ---------------- prep A: mask -> float multiplier (auto-detect dtype) -----
__global__ void k_mask(const void* __restrict__ mraw, float* __restrict__ fm) {
  __shared__ int bad[2];
  int t = threadIdx.x;
  if (t < 2) bad[t] = 0;
  __syncthreads();
  const uint32_t* w = (const uint32_t*)mraw;
  int b0 = 0, b1 = 0;
  for (int i = t; i < 4096; i += 256) {      // scan 16KB: safe under u8/i32/f32
    uint32_t v = w[i];
    b0 |= !(v == 0u || v == 1u);             // violates int32-bool pattern
    b1 |= !(v == 0u || v == 0x3F800000u);    // violates float-bool pattern
  }
  if (b0) atomicOr(&bad[0], 1);
  if (b1) atomicOr(&bad[1], 1);
  __syncthreads();
  int u8mode = bad[0] && bad[1];             // packed bytes
  const uint8_t* p8 = (const uint8_t*)mraw;
  for (int i = t; i < MTOT; i += 256) {
    int mv = u8mode ? (p8[i] != 0) : (w[i] != 0u);
    fm[i] = mv ? 0.0f : 1.0f;                // True = masked out -> weight 0
  }
}

// ---------------- prep B: W [1024][64] f32 -> Wt [3][64][1024] bf16 --------
__global__ void k_prepw(const float* __restrict__ Wq, const float* __restrict__ Wk,
                        const float* __restrict__ Wv, __bf16* __restrict__ Wt) {
  __shared__ float tile[64][65];
  int bid = blockIdx.x;
  int m = bid >> 4;                 // 0=q 1=k 2=v
  int k0 = (bid & 15) * 64;
  const float* W = (m == 0) ? Wq : (m == 1 ? Wk : Wv);
  float sc = (m == 0) ? SCALE : 1.0f;
  int t = threadIdx.x;
  #pragma unroll
  for (int i = 0; i < 16; i++) {
    int idx = i*256 + t;
    tile[idx >> 6][idx & 63] = W[(size_t)(k0 + (idx >> 6))*DOUT + (idx & 63)] * sc;
  }
  __syncthreads();
  #pragma unroll
  for (int i = 0; i < 16; i++) {
    int idx = i*256 + t;
    int n = idx >> 6, kk = idx & 63;
    Wt[(size_t)(m*DOUT + n)*DIN + k0 + kk] = (__bf16)tile[kk][n];
  }
}

// ---------------- pass 1: QKV projection GEMM ------------------------------
// grid 256 (BM=64 rows), 256 thr (4 waves x 16 rows). A from global, B in LDS.
__global__ __launch_bounds__(256) void k_qkv(
    const float* __restrict__ seq, const __bf16* __restrict__ Wt,
    const float* __restrict__ bq, const float* __restrict__ bk,
    const float* __restrict__ bv,
    __bf16* __restrict__ Qo, __bf16* __restrict__ Ko, __bf16* __restrict__ Vto) {
  __shared__ uint8_t bsm[192*128];   // Bt [192 rows(n)][64 k] bf16, 16B-unit XOR swizzle
  int t = threadIdx.x;
  int wave = t >> 6, lane = t & 63, lg = lane >> 4, ll = lane & 15;
  int m0 = blockIdx.x * 64;
  int arow = m0 + wave*16 + ll;
  const float* abase = seq + (size_t)arow * DIN;

  f32x4 acur[2][2];                  // prefetched A: [kk][lo/hi]
  #pragma unroll
  for (int kk = 0; kk < 2; kk++) {
    const float* ap = abase + kk*32 + lg*8;
    acur[kk][0] = *(const f32x4*)(ap);
    acur[kk][1] = *(const f32x4*)(ap + 4);
  }
  f32x4 acc[12];
  #pragma unroll
  for (int i = 0; i < 12; i++) acc[i] = f32x4{0.f,0.f,0.f,0.f};

  for (int c = 0; c < 16; c++) {
    int k0 = c * 64;
    __syncthreads();
    // stage Bt chunk: 192 rows x 64 k bf16 = 24KB, swizzled units
    #pragma unroll
    for (int j = 0; j < 6; j++) {
      int flat = j*256 + t;          // 0..1535
      int R = flat >> 3, u = flat & 7;
      short8 v = *(const short8*)((const uint8_t*)Wt + (size_t)R*2048 + (size_t)k0*2 + u*16);
      *(short8*)(bsm + R*128 + ((u ^ (R & 7)) * 16)) = v;
    }
    __syncthreads();
    // convert current A to bf16 frags
    short8 ab[2];
    #pragma unroll
    for (int kk = 0; kk < 2; kk++)
      #pragma unroll
      for (int j = 0; j < 8; j++)
        ab[kk][j] = f2bf(j < 4 ? acur[kk][0][j] : acur[kk][1][j-4]);
    // prefetch next chunk's A
    if (c < 15) {
      #pragma unroll
      for (int kk = 0; kk < 2; kk++) {
        const float* ap = abase + (k0 + 64) + kk*32 + lg*8;
        acur[kk][0] = *(const f32x4*)(ap);
        acur[kk][1] = *(const f32x4*)(ap + 4);
      }
    }
    #pragma unroll
    for (int kk = 0; kk < 2; kk++) {
      #pragma unroll
      for (int mm = 0; mm < 12; mm++) {
        int R = mm*16 + ll;
        int u = kk*4 + lg;
        short8 bb = *(const short8*)(bsm + R*128 + ((u ^ (R & 7)) * 16));
        acc[mm] = __builtin_amdgcn_mfma_f32_16x16x32_bf16(ab[kk], bb, acc[mm], 0, 0, 0);
      }
    }
  }
  // epilogue: C row = (lane>>4)*4 + r, col = lane&15 (+16*nf)
  int orow = m0 + wave*16 + lg*4;
  int bb_ = orow >> 11;
  int sloc = orow & 2047;
  #pragma unroll
  for (int mm = 0; mm < 12; mm++) {
    int mat = mm >> 2;
    int col = (mm & 3)*16 + ll;
    float bias = (mat == 0) ? bq[col]*SCALE : (mat == 1 ? bk[col] : bv[col]);
    if (mat == 0) {
      #pragma unroll
      for (int r = 0; r < 4; r++)
        Qo[(size_t)(orow + r)*DOUT + col] = (__bf16)(acc[mm][r] + bias);
    } else if (mat == 1) {
      #pragma unroll
      for (int r = 0; r < 4; r++)
        Ko[(size_t)(orow + r)*DOUT + col] = (__bf16)(acc[mm][r] + bias);
    } else {
      us4 pk;
      #pragma unroll
      for (int r = 0; r < 4; r++) pk[r] = (unsigned short)f2bf(acc[mm][r] + bias);
      *(us4*)((uint8_t*)Vto + ((size_t)(bb_*DOUT + col)*SS + sloc)*2) = pk;  // transposed V
    }
  }
}

// ---------------- pass 2: masked softmax attention -------------------------
// grid 256 = (b, 64-row q tile), 256 thr (4 waves x 16 q rows). No max-tracking
// (|scores| < ~0.4): p = mask * exp(s); ctx = (sum p v)/(sum p).
__global__ __launch_bounds__(256) void k_attn(
    const __bf16* __restrict__ Q, const __bf16* __restrict__ Kd,
    const __bf16* __restrict__ Vt, const float* __restrict__ fm,
    float* __restrict__ out) {
  __shared__ uint8_t smem[57344];
  // K: [128 keys][64 d] @0 (swz ^(key&7)); V: [64 d][128 keys] @16384 (swz ^(d&15));
  // P: per-wave [16 q][128 keys] @32768+wave*4096 (swz ^(q&15)); fmask @49152 (8KB)
  float* fml = (float*)(smem + 49152);
  int t = threadIdx.x, wave = t >> 6, lane = t & 63, lg = lane >> 4, ll = lane & 15;
  int b = blockIdx.x >> 5, qt = blockIdx.x & 31;
  int q0 = qt*64 + wave*16;

  for (int i = t; i < SS; i += 256) fml[i] = fm[b*SS + i];

  const uint8_t* qbase = (const uint8_t*)Q + ((size_t)(b*SS + q0 + ll))*128;
  short8 aq[2];
  aq[0] = *(const short8*)(qbase + lg*16);
  aq[1] = *(const short8*)(qbase + 64 + lg*16);

  f32x4 oacc[4];
  #pragma unroll
  for (int i = 0; i < 4; i++) oacc[i] = f32x4{0.f,0.f,0.f,0.f};
  float den[4] = {0.f, 0.f, 0.f, 0.f};

  const uint8_t* kgbase = (const uint8_t*)Kd + (size_t)b*SS*128;
  const uint8_t* vgbase = (const uint8_t*)Vt + (size_t)b*DOUT*SS*2;
  uint8_t* pbase = smem + 32768 + wave*4096;

  for (int kb = 0; kb < 16; kb++) {
    __syncthreads();
    #pragma unroll
    for (int j = 0; j < 4; j++) {        // stage K chunk (16KB)
      int flat = j*256 + t;
      int key = flat >> 3, u = flat & 7;
      short8 v = *(const short8*)(kgbase + (size_t)(kb*128 + key)*128 + u*16);
      *(short8*)(smem + key*128 + ((u ^ (key & 7)) * 16)) = v;
    }
    #pragma unroll
    for (int j = 0; j < 4; j++) {        // stage V chunk (16KB)
      int flat = j*256 + t;
      int d = flat >> 4, u = flat & 15;
      short8 v = *(const short8*)(vgbase + ((size_t)d*SS + kb*128)*2 + u*16);
      *(short8*)(smem + 16384 + d*256 + ((u ^ (d & 15)) * 16)) = v;
    }
    __syncthreads();
    // QK^T
    f32x4 sacc[8];
    #pragma unroll
    for (int i = 0; i < 8; i++) sacc[i] = f32x4{0.f,0.f,0.f,0.f};
    #pragma unroll
    for (int kk = 0; kk < 2; kk++) {
      #pragma unroll
      for (int nf = 0; nf < 8; nf++) {
        int key = nf*16 + ll;
        int u = kk*4 + lg;
        short8 kf = *(const short8*)(smem + key*128 + ((u ^ (key & 7)) * 16));
        sacc[nf] = __builtin_amdgcn_mfma_f32_16x16x32_bf16(aq[kk], kf, sacc[nf], 0, 0, 0);
      }
    }
    // p = mask * exp(s); write bf16 P to per-wave LDS; accumulate denominator
    #pragma unroll
    for (int nf = 0; nf < 8; nf++) {
      float msk = fml[kb*128 + nf*16 + ll];
      #pragma unroll
      for (int r = 0; r < 4; r++) {
        float p = msk * __expf(sacc[nf][r]);
        __bf16 pb = (__bf16)p;
        den[r] += (float)pb;             // match PV's bf16-rounded numerator
        int qrow = lg*4 + r;
        int col = nf*16 + ll;
        *(__bf16*)(pbase + qrow*256 + (((col >> 3) ^ qrow) * 16) + (col & 7)*2) = pb;
      }
    }
    // PV (per-wave-private P: no barrier needed, lgkmcnt handled by compiler)
    #pragma unroll
    for (int ks = 0; ks < 4; ks++) {
      int u = ks*4 + lg;
      short8 pf = *(const short8*)(pbase + ll*256 + ((u ^ ll) * 16));
      #pragma unroll
      for (int df = 0; df < 4; df++) {
        int d = df*16 + ll;
        short8 vf = *(const short8*)(smem + 16384 + d*256 + ((u ^ (d & 15)) * 16));
        oacc[df] = __builtin_amdgcn_mfma_f32_16x16x32_bf16(pf, vf, oacc[df], 0, 0, 0);
      }
    }
  }
  // denominator: reduce across the 16 lanes sharing this C-fragment row group
  #pragma unroll
  for (int r = 0; r < 4; r++) {
    float d = den[r];
    d += __shfl_xor(d, 1, 64);
    d += __shfl_xor(d, 2, 64);
    d += __shfl_xor(d, 4, 64);
    d += __shfl_xor(d, 8, 64);
    den[r] = d;
  }
  #pragma unroll
  for (int df = 0; df < 4; df++) {
    int col = df*16 + ll;
    #pragma unroll
    for (int r = 0; r < 4; r++) {
      int gq = b*SS + q0 + lg*4 + r;
      out[(size_t)gq*DOUT + col] = oacc[df][r] / den[r];
    }
  }
}

extern "C" void kernel_launch(void* const* d_in, const int* in_sizes, int n_in,
                              void* d_out, int out_size, void* d_ws, size_t ws_size,
                              hipStream_t stream) {
  const float* seq = (const float*)d_in[0];
  const void*  msk = d_in[1];
  const float* Wq  = (const float*)d_in[2];
  const float* bq  = (const float*)d_in[3];
  const float* Wk  = (const float*)d_in[4];
  const float* bk  = (const float*)d_in[5];
  const float* Wv  = (const float*)d_in[6];
  const float* bv  = (const float*)d_in[7];
  uint8_t* ws = (uint8_t*)d_ws;
  __bf16* Wt  = (__bf16*)(ws + WT_OFF);
  float*  fm  = (float*)(ws + FM_OFF);
  __bf16* Qb  = (__bf16*)(ws + Q_OFF);
  __bf16* Kb  = (__bf16*)(ws + K_OFF);
  __bf16* Vtb = (__bf16*)(ws + VT_OFF);
  float* out  = (float*)d_out;

  k_mask<<<dim3(1), dim3(256), 0, stream>>>(msk, fm);
  k_prepw<<<dim3(48), dim3(256), 0, stream>>>(Wq, Wk, Wv, Wt);
  k_qkv<<<dim3(256), dim3(256), 0, stream>>>(seq, Wt, bq, bk, bv, Qb, Kb, Vtb);
  k_attn<<<dim3(256), dim3(256), 0, stream>>>(Qb, Kb, Vtb, fm, out);
}

// Round 2
// 147.609 us; speedup vs baseline: 1.2092x; 1.2092x over previous
//
#include <hip/hip_runtime.h>
#include <hip/hip_bf16.h>
#include <stdint.h>

#define NB 8
#define SS 2048
#define DIN 1024
#define DOUT 64
#define MTOT (NB*SS)
#define SCALE 0.02209708691207961f   // 1/sqrt(2048)

typedef short  short8 __attribute__((ext_vector_type(8)));
typedef float  f32x4  __attribute__((ext_vector_type(4)));
typedef unsigned short us4 __attribute__((ext_vector_type(4)));

// workspace layout (bytes)
#define WT_OFF 0                       // bf16 [192][1024] (q-scale folded)
#define FM_OFF 393216                  // float [16384]
#define Q_OFF  524288                  // bf16 [16384][64]
#define K_OFF  (Q_OFF + MTOT*DOUT*2)
#define VT_OFF (K_OFF + MTOT*DOUT*2)   // bf16 [8][64][2048] (V transposed)

__device__ __forceinline__ short f2bf(float f) {
  __bf16 h = (__bf16)f;
  return __builtin_bit_cast(short, h);
}

// global -> LDS direct copy, 16B per lane. l must be the WAVE-UNIFORM base;
// HW adds lane*16. Source address is per-lane (this is where swizzles live).
__device__ __forceinline__ void gl_lds16(const void* g, void* l) {
  __builtin_amdgcn_global_load_lds(
      (const __attribute__((address_space(1))) uint32_t*)g,
      (__attribute__((address_space(3))) uint32_t*)l, 16, 0, 0);
}

// ---------------- prep: W convert + mask expand (one kernel) ---------------
// blocks 0..47: Wt [192 rows(n)][1024 k] bf16; blocks 48..111: mask -> fm
__global__ void k_prep(const float* __restrict__ Wq, const float* __restrict__ Wk,
                       const float* __restrict__ Wv, const void* __restrict__ mraw,
                       __bf16* __restrict__ Wt, float* __restrict__ fm) {
  int bid = blockIdx.x, t = threadIdx.x;
  if (bid < 48) {
    __shared__ float tile[64][65];
    int m = bid >> 4;                 // 0=q 1=k 2=v
    int k0 = (bid & 15) * 64;
    const float* W = (m == 0) ? Wq : (m == 1 ? Wk : Wv);
    float sc = (m == 0) ? SCALE : 1.0f;
    #pragma unroll
    for (int i = 0; i < 16; i++) {
      int idx = i*256 + t;
      tile[idx >> 6][idx & 63] = W[(size_t)(k0 + (idx >> 6))*DOUT + (idx & 63)] * sc;
    }
    __syncthreads();
    #pragma unroll
    for (int i = 0; i < 16; i++) {
      int idx = i*256 + t;
      int n = idx >> 6, kk = idx & 63;
      Wt[(size_t)(m*DOUT + n)*DIN + k0 + kk] = (__bf16)tile[kk][n];
    }
  } else {
    __shared__ int bad[2];
    if (t < 2) bad[t] = 0;
    __syncthreads();
    const uint32_t* w = (const uint32_t*)mraw;
    int b0 = 0, b1 = 0;
    for (int i = t; i < 4096; i += 256) {   // scan first 16KB: consistent across blocks
      uint32_t v = w[i];
      b0 |= !(v == 0u || v == 1u);
      b1 |= !(v == 0u || v == 0x3F800000u);
    }
    if (b0) atomicOr(&bad[0], 1);
    if (b1) atomicOr(&bad[1], 1);
    __syncthreads();
    int u8mode = bad[0] && bad[1];
    const uint8_t* p8 = (const uint8_t*)mraw;
    int i = (bid - 48)*256 + t;
    int mv = u8mode ? (p8[i] != 0) : (w[i] != 0u);
    fm[i] = mv ? 0.0f : 1.0f;
  }
}

// ---------------- pass 1: QKV projection GEMM ------------------------------
// grid 256 (BM=64), 256 thr (4 waves x 16 rows). Double-buffered LDS via
// global_load_lds (linear dest + swizzled per-lane SOURCE). 2-phase pipeline:
// STAGE(c+1) -> COMPUTE(c) -> __syncthreads (one drain per tile).
__global__ __launch_bounds__(256) void k_qkv(
    const float* __restrict__ seq, const __bf16* __restrict__ Wt,
    const float* __restrict__ bq, const float* __restrict__ bk,
    const float* __restrict__ bv,
    __bf16* __restrict__ Qo, __bf16* __restrict__ Ko, __bf16* __restrict__ Vto) {
  __shared__ uint8_t smem[81920];     // 2 x (A 16KB f32 [64][16 units] + B 24KB [192][8 units])
  int t = threadIdx.x, w = t >> 6, lane = t & 63, lg = lane >> 4, ll = lane & 15;
  int m0 = blockIdx.x * 64;
  const uint8_t* seqB = (const uint8_t*)seq;
  const uint8_t* WtB  = (const uint8_t*)Wt;

  f32x4 acc[12];
  #pragma unroll
  for (int i = 0; i < 12; i++) acc[i] = f32x4{0.f,0.f,0.f,0.f};

  auto STAGE = [&](int c) {
    uint8_t* bufA = smem + (c & 1)*40960;
    uint8_t* bufB = bufA + 16384;
    #pragma unroll
    for (int j = 0; j < 4; j++) {     // A: 64 rows x 256B, unit swizzle sa(r)
      int g = j*256 + w*64 + lane;
      int r = g >> 4, u1 = g & 15;
      int u = u1 ^ (((r & 7) << 1) | ((r >> 3) & 1));
      gl_lds16(seqB + (size_t)(m0 + r)*4096 + c*256 + u*16,
               bufA + (j*256 + w*64)*16);
    }
    #pragma unroll
    for (int j = 0; j < 6; j++) {     // B: 192 rows x 128B, unit swizzle R&7
      int g = j*256 + w*64 + lane;
      int R = g >> 3, u1 = g & 7;
      int u = u1 ^ (R & 7);
      gl_lds16(WtB + (size_t)R*2048 + c*128 + u*16,
               bufB + (j*256 + w*64)*16);
    }
  };

  STAGE(0);
  __syncthreads();
  for (int c = 0; c < 16; c++) {
    if (c < 15) STAGE(c + 1);
    uint8_t* bufA = smem + (c & 1)*40960;
    uint8_t* bufB = bufA + 16384;
    int r = w*16 + ll;
    int sa = ((r & 7) << 1) | ((r >> 3) & 1);
    short8 ab[2];
    #pragma unroll
    for (int kk = 0; kk < 2; kk++) {
      f32x4 a0 = *(const f32x4*)(bufA + r*256 + (((kk*8 + lg*2    ) ^ sa)*16));
      f32x4 a1 = *(const f32x4*)(bufA + r*256 + (((kk*8 + lg*2 + 1) ^ sa)*16));
      #pragma unroll
      for (int j = 0; j < 4; j++) { ab[kk][j] = f2bf(a0[j]); ab[kk][4+j] = f2bf(a1[j]); }
    }
    #pragma unroll
    for (int kk = 0; kk < 2; kk++) {
      #pragma unroll
      for (int mm = 0; mm < 12; mm++) {
        int R = mm*16 + ll;
        short8 bb = *(const short8*)(bufB + R*128 + (((kk*4 + lg) ^ (R & 7))*16));
        acc[mm] = __builtin_amdgcn_mfma_f32_16x16x32_bf16(ab[kk], bb, acc[mm], 0, 0, 0);
      }
    }
    __syncthreads();
  }

  // epilogue: C row = lg*4 + r, col = ll (+16*frag)
  int orow = m0 + w*16 + lg*4;
  int bb_  = orow >> 11;
  int sloc = orow & 2047;
  #pragma unroll
  for (int mm = 0; mm < 12; mm++) {
    int mat = mm >> 2;
    int col = (mm & 3)*16 + ll;
    float bias = (mat == 0) ? bq[col]*SCALE : (mat == 1 ? bk[col] : bv[col]);
    if (mat == 0) {
      #pragma unroll
      for (int rr = 0; rr < 4; rr++)
        Qo[(size_t)(orow + rr)*DOUT + col] = (__bf16)(acc[mm][rr] + bias);
    } else if (mat == 1) {
      #pragma unroll
      for (int rr = 0; rr < 4; rr++)
        Ko[(size_t)(orow + rr)*DOUT + col] = (__bf16)(acc[mm][rr] + bias);
    } else {
      us4 pk;
      #pragma unroll
      for (int rr = 0; rr < 4; rr++) pk[rr] = (unsigned short)f2bf(acc[mm][rr] + bias);
      *(us4*)((uint8_t*)Vto + ((size_t)(bb_*DOUT + col)*SS + sloc)*2) = pk;
    }
  }
}

// ---------------- pass 2: masked softmax attention -------------------------
// grid 256 = (b, 64-q tile), 256 thr. Double-buffered K/V via global_load_lds,
// 2-phase pipeline, one __syncthreads per key-chunk. No max-tracking
// (|scores| < ~0.4): p = mask * exp(s); ctx = (sum p v)/(sum p).
__global__ __launch_bounds__(256) void k_attn(
    const __bf16* __restrict__ Q, const __bf16* __restrict__ Kd,
    const __bf16* __restrict__ Vt, const float* __restrict__ fm,
    float* __restrict__ out) {
  __shared__ uint8_t smem[90112];
  // buf(i)=smem+i*32768: [K 16KB [128 keys][8u]][V 16KB [64 d][16u]]
  // P: 65536 + wave*4096; fmask f32: 81920 (8KB)
  float* fml = (float*)(smem + 81920);
  int t = threadIdx.x, w = t >> 6, lane = t & 63, lg = lane >> 4, ll = lane & 15;
  int b = blockIdx.x >> 5, qt = blockIdx.x & 31;
  int q0 = qt*64 + w*16;

  for (int i = t; i < SS; i += 256) fml[i] = fm[b*SS + i];

  const uint8_t* qbase = (const uint8_t*)Q + ((size_t)(b*SS + q0 + ll))*128;
  short8 aq[2];
  aq[0] = *(const short8*)(qbase + lg*16);
  aq[1] = *(const short8*)(qbase + 64 + lg*16);

  f32x4 oacc[4];
  #pragma unroll
  for (int i = 0; i < 4; i++) oacc[i] = f32x4{0.f,0.f,0.f,0.f};
  float den[4] = {0.f, 0.f, 0.f, 0.f};

  const uint8_t* kgb = (const uint8_t*)Kd + (size_t)b*SS*128;
  const uint8_t* vgb = (const uint8_t*)Vt + (size_t)b*DOUT*SS*2;
  uint8_t* pbase = smem + 65536 + w*4096;

  auto STAGE = [&](int kb, int bi) {
    uint8_t* bk_ = smem + bi*32768;
    uint8_t* bv_ = bk_ + 16384;
    #pragma unroll
    for (int j = 0; j < 4; j++) {     // K chunk: 128 rows x 128B
      int g = j*256 + w*64 + lane;
      int key = g >> 3, u1 = g & 7;
      int u = u1 ^ (key & 7);
      gl_lds16(kgb + (size_t)(kb*128 + key)*128 + u*16, bk_ + (j*256 + w*64)*16);
    }
    #pragma unroll
    for (int j = 0; j < 4; j++) {     // V chunk: 64 rows x 256B
      int g = j*256 + w*64 + lane;
      int d = g >> 4, u1 = g & 15;
      int u = u1 ^ (d & 15);
      gl_lds16(vgb + (size_t)d*4096 + kb*256 + u*16, bv_ + (j*256 + w*64)*16);
    }
  };

  STAGE(0, 0);
  __syncthreads();
  for (int kb = 0; kb < 16; kb++) {
    if (kb < 15) STAGE(kb + 1, (kb + 1) & 1);
    uint8_t* bk_ = smem + (kb & 1)*32768;
    uint8_t* bv_ = bk_ + 16384;
    // QK^T
    f32x4 sacc[8];
    #pragma unroll
    for (int i = 0; i < 8; i++) sacc[i] = f32x4{0.f,0.f,0.f,0.f};
    #pragma unroll
    for (int kk = 0; kk < 2; kk++) {
      #pragma unroll
      for (int nf = 0; nf < 8; nf++) {
        int key = nf*16 + ll;
        short8 kf = *(const short8*)(bk_ + key*128 + (((kk*4 + lg) ^ (key & 7))*16));
        sacc[nf] = __builtin_amdgcn_mfma_f32_16x16x32_bf16(aq[kk], kf, sacc[nf], 0, 0, 0);
      }
    }
    // p = mask * exp(s); bf16 P -> per-wave LDS; accumulate denominator
    #pragma unroll
    for (int nf = 0; nf < 8; nf++) {
      float msk = fml[kb*128 + nf*16 + ll];
      #pragma unroll
      for (int r = 0; r < 4; r++) {
        float p = msk * __expf(sacc[nf][r]);
        __bf16 pb = (__bf16)p;
        den[r] += (float)pb;
        int qrow = lg*4 + r;
        int col = nf*16 + ll;
        *(__bf16*)(pbase + qrow*256 + (((col >> 3) ^ qrow)*16) + (col & 7)*2) = pb;
      }
    }
    // PV
    #pragma unroll
    for (int ks = 0; ks < 4; ks++) {
      int u = ks*4 + lg;
      short8 pf = *(const short8*)(pbase + ll*256 + ((u ^ ll)*16));
      #pragma unroll
      for (int df = 0; df < 4; df++) {
        int d = df*16 + ll;
        short8 vf = *(const short8*)(bv_ + d*256 + ((u ^ (d & 15))*16));
        oacc[df] = __builtin_amdgcn_mfma_f32_16x16x32_bf16(pf, vf, oacc[df], 0, 0, 0);
      }
    }
    __syncthreads();
  }
  // denominator: reduce across the 16 lanes sharing each C-fragment row group
  #pragma unroll
  for (int r = 0; r < 4; r++) {
    float d = den[r];
    d += __shfl_xor(d, 1, 64);
    d += __shfl_xor(d, 2, 64);
    d += __shfl_xor(d, 4, 64);
    d += __shfl_xor(d, 8, 64);
    den[r] = d;
  }
  #pragma unroll
  for (int df = 0; df < 4; df++) {
    int col = df*16 + ll;
    #pragma unroll
    for (int r = 0; r < 4; r++) {
      int gq = b*SS + q0 + lg*4 + r;
      out[(size_t)gq*DOUT + col] = oacc[df][r] / den[r];
    }
  }
}

extern "C" void kernel_launch(void* const* d_in, const int* in_sizes, int n_in,
                              void* d_out, int out_size, void* d_ws, size_t ws_size,
                              hipStream_t stream) {
  const float* seq = (const float*)d_in[0];
  const void*  msk = d_in[1];
  const float* Wq  = (const float*)d_in[2];
  const float* bq  = (const float*)d_in[3];
  const float* Wk  = (const float*)d_in[4];
  const float* bk  = (const float*)d_in[5];
  const float* Wv  = (const float*)d_in[6];
  const float* bv  = (const float*)d_in[7];
  uint8_t* ws = (uint8_t*)d_ws;
  __bf16* Wt  = (__bf16*)(ws + WT_OFF);
  float*  fm  = (float*)(ws + FM_OFF);
  __bf16* Qb  = (__bf16*)(ws + Q_OFF);
  __bf16* Kb  = (__bf16*)(ws + K_OFF);
  __bf16* Vtb = (__bf16*)(ws + VT_OFF);
  float* out  = (float*)d_out;

  k_prep<<<dim3(112), dim3(256), 0, stream>>>(Wq, Wk, Wv, msk, Wt, fm);
  k_qkv<<<dim3(256), dim3(256), 0, stream>>>(seq, Wt, bq, bk, bv, Qb, Kb, Vtb);
  k_attn<<<dim3(256), dim3(256), 0, stream>>>(Qb, Kb, Vtb, fm, out);
}

// Round 3
// 143.752 us; speedup vs baseline: 1.2417x; 1.0268x over previous
//
#include <hip/hip_runtime.h>
#include <hip/hip_bf16.h>
#include <stdint.h>

#define NB 8
#define SS 2048
#define DIN 1024
#define DOUT 64
#define MTOT (NB*SS)
#define SCALE 0.02209708691207961f   // 1/sqrt(2048)

typedef short  short8 __attribute__((ext_vector_type(8)));
typedef float  f32x4  __attribute__((ext_vector_type(4)));
typedef unsigned short us4 __attribute__((ext_vector_type(4)));

// workspace layout (bytes)
#define WT_OFF 0                       // bf16 [192][1024] (q-scale folded)
#define FM_OFF 393216                  // float [16384]
#define Q_OFF  524288                  // bf16 [16384][64]
#define K_OFF  (Q_OFF + MTOT*DOUT*2)
#define VT_OFF (K_OFF + MTOT*DOUT*2)   // bf16 [8][64][2048] (V transposed)

__device__ __forceinline__ short f2bf(float f) {
  __bf16 h = (__bf16)f;
  return __builtin_bit_cast(short, h);
}

// global -> LDS direct copy, 16B per lane. l is the WAVE-UNIFORM base;
// HW adds lane*16. Source address is per-lane (swizzles live there).
__device__ __forceinline__ void gl_lds16(const void* g, void* l) {
  __builtin_amdgcn_global_load_lds(
      (const __attribute__((address_space(1))) uint32_t*)g,
      (__attribute__((address_space(3))) uint32_t*)l, 16, 0, 0);
}

// ---------------- prep: W convert + mask expand (one kernel) ---------------
__global__ void k_prep(const float* __restrict__ Wq, const float* __restrict__ Wk,
                       const float* __restrict__ Wv, const void* __restrict__ mraw,
                       __bf16* __restrict__ Wt, float* __restrict__ fm) {
  int bid = blockIdx.x, t = threadIdx.x;
  if (bid < 48) {
    __shared__ float tile[64][65];
    int m = bid >> 4;                 // 0=q 1=k 2=v
    int k0 = (bid & 15) * 64;
    const float* W = (m == 0) ? Wq : (m == 1 ? Wk : Wv);
    float sc = (m == 0) ? SCALE : 1.0f;
    #pragma unroll
    for (int i = 0; i < 16; i++) {
      int idx = i*256 + t;
      tile[idx >> 6][idx & 63] = W[(size_t)(k0 + (idx >> 6))*DOUT + (idx & 63)] * sc;
    }
    __syncthreads();
    #pragma unroll
    for (int i = 0; i < 16; i++) {
      int idx = i*256 + t;
      int n = idx >> 6, kk = idx & 63;
      Wt[(size_t)(m*DOUT + n)*DIN + k0 + kk] = (__bf16)tile[kk][n];
    }
  } else {
    __shared__ int bad[2];
    if (t < 2) bad[t] = 0;
    __syncthreads();
    const uint32_t* w = (const uint32_t*)mraw;
    int b0 = 0, b1 = 0;
    for (int i = t; i < 4096; i += 256) {
      uint32_t v = w[i];
      b0 |= !(v == 0u || v == 1u);
      b1 |= !(v == 0u || v == 0x3F800000u);
    }
    if (b0) atomicOr(&bad[0], 1);
    if (b1) atomicOr(&bad[1], 1);
    __syncthreads();
    int u8mode = bad[0] && bad[1];
    const uint8_t* p8 = (const uint8_t*)mraw;
    int i = (bid - 48)*256 + t;
    int mv = u8mode ? (p8[i] != 0) : (w[i] != 0u);
    fm[i] = mv ? 0.0f : 1.0f;
  }
}

// ---------------- pass 1: QKV projection GEMM ------------------------------
// grid 256 (BM=64), 256 thr. 3-buffer LDS pipeline, counted vmcnt (T3+T4):
// loads stay in flight across barriers; never vmcnt(0) in steady state.
__global__ __launch_bounds__(256) void k_qkv(
    const float* __restrict__ seq, const __bf16* __restrict__ Wt,
    const float* __restrict__ bq, const float* __restrict__ bk,
    const float* __restrict__ bv,
    __bf16* __restrict__ Qo, __bf16* __restrict__ Ko, __bf16* __restrict__ Vto) {
  __shared__ uint8_t smem[122880];    // 3 x (A 16KB f32 [64 r][16 u] + B 24KB [192 R][8 u])
  int t = threadIdx.x, w = t >> 6, lane = t & 63, lg = lane >> 4, ll = lane & 15;
  int m0 = blockIdx.x * 64;
  const uint8_t* seqB = (const uint8_t*)seq;
  const uint8_t* WtB  = (const uint8_t*)Wt;

  f32x4 acc[12];
  #pragma unroll
  for (int i = 0; i < 12; i++) acc[i] = f32x4{0.f,0.f,0.f,0.f};

  auto STAGE = [&](int c, int bi) {   // 10 gl_lds per wave
    uint8_t* bufA = smem + bi*40960;
    uint8_t* bufB = bufA + 16384;
    #pragma unroll
    for (int j = 0; j < 4; j++) {     // A: 64 rows x 256B, unit swizzle sa(r)
      int g = j*256 + w*64 + lane;
      int r = g >> 4, u1 = g & 15;
      int u = u1 ^ (((r & 7) << 1) | ((r >> 3) & 1));
      gl_lds16(seqB + (size_t)(m0 + r)*4096 + c*256 + u*16,
               bufA + (j*256 + w*64)*16);
    }
    #pragma unroll
    for (int j = 0; j < 6; j++) {     // B: 192 rows x 128B, unit swizzle R&7
      int g = j*256 + w*64 + lane;
      int R = g >> 3, u1 = g & 7;
      int u = u1 ^ (R & 7);
      gl_lds16(WtB + (size_t)R*2048 + c*128 + u*16,
               bufB + (j*256 + w*64)*16);
    }
  };

  STAGE(0, 0);
  STAGE(1, 1);
  #pragma unroll
  for (int c = 0; c < 16; c++) {
    // S(c) done; S(c+1) (10 loads) may stay outstanding across the barrier
    if (c < 15) asm volatile("s_waitcnt vmcnt(10)" ::: "memory");
    else        asm volatile("s_waitcnt vmcnt(0)"  ::: "memory");
    __builtin_amdgcn_s_barrier();
    __builtin_amdgcn_sched_barrier(0);
    if (c + 2 < 16) STAGE(c + 2, (c + 2) % 3);

    uint8_t* bufA = smem + (c % 3)*40960;
    uint8_t* bufB = bufA + 16384;
    int r = w*16 + ll;
    int sa = ((r & 7) << 1) | ((r >> 3) & 1);
    short8 ab[2];
    #pragma unroll
    for (int kk = 0; kk < 2; kk++) {
      f32x4 a0 = *(const f32x4*)(bufA + r*256 + (((kk*8 + lg*2    ) ^ sa)*16));
      f32x4 a1 = *(const f32x4*)(bufA + r*256 + (((kk*8 + lg*2 + 1) ^ sa)*16));
      #pragma unroll
      for (int j = 0; j < 4; j++) { ab[kk][j] = f2bf(a0[j]); ab[kk][4+j] = f2bf(a1[j]); }
    }
    #pragma unroll
    for (int kk = 0; kk < 2; kk++) {
      #pragma unroll
      for (int mm = 0; mm < 12; mm++) {
        int R = mm*16 + ll;
        short8 bb = *(const short8*)(bufB + R*128 + (((kk*4 + lg) ^ (R & 7))*16));
        acc[mm] = __builtin_amdgcn_mfma_f32_16x16x32_bf16(ab[kk], bb, acc[mm], 0, 0, 0);
      }
    }
  }

  // epilogue: C row = lg*4 + rr, col = ll (+16*frag)
  int orow = m0 + w*16 + lg*4;
  int bb_  = orow >> 11;
  int sloc = orow & 2047;
  #pragma unroll
  for (int mm = 0; mm < 12; mm++) {
    int mat = mm >> 2;
    int col = (mm & 3)*16 + ll;
    float bias = (mat == 0) ? bq[col]*SCALE : (mat == 1 ? bk[col] : bv[col]);
    if (mat == 0) {
      #pragma unroll
      for (int rr = 0; rr < 4; rr++)
        Qo[(size_t)(orow + rr)*DOUT + col] = (__bf16)(acc[mm][rr] + bias);
    } else if (mat == 1) {
      #pragma unroll
      for (int rr = 0; rr < 4; rr++)
        Ko[(size_t)(orow + rr)*DOUT + col] = (__bf16)(acc[mm][rr] + bias);
    } else {
      us4 pk;
      #pragma unroll
      for (int rr = 0; rr < 4; rr++) pk[rr] = (unsigned short)f2bf(acc[mm][rr] + bias);
      *(us4*)((uint8_t*)Vto + ((size_t)(bb_*DOUT + col)*SS + sloc)*2) = pk;
    }
  }
}

// ---------------- pass 2: masked softmax attention -------------------------
// grid 256 = (b, 64-q tile), 256 thr. 3-buffer K/V pipeline, counted vmcnt.
// No max-tracking (|scores| < ~0.4): p = mask*exp(s); ctx = (sum p v)/(sum p).
__global__ __launch_bounds__(256) void k_attn(
    const __bf16* __restrict__ Q, const __bf16* __restrict__ Kd,
    const __bf16* __restrict__ Vt, const float* __restrict__ fm,
    float* __restrict__ out) {
  __shared__ uint8_t smem[122880];
  // buf(i)=smem+i*32768 (i<3): [K 16KB [128 keys][8u]][V 16KB [64 d][16u]]
  // P: 98304 + wave*4096 (16KB); fmask f32: 114688 (8KB)
  float* fml = (float*)(smem + 114688);
  int t = threadIdx.x, w = t >> 6, lane = t & 63, lg = lane >> 4, ll = lane & 15;
  int b = blockIdx.x >> 5, qt = blockIdx.x & 31;
  int q0 = qt*64 + w*16;

  for (int i = t; i < SS; i += 256) fml[i] = fm[b*SS + i];

  const uint8_t* qbase = (const uint8_t*)Q + ((size_t)(b*SS + q0 + ll))*128;
  short8 aq[2];
  aq[0] = *(const short8*)(qbase + lg*16);
  aq[1] = *(const short8*)(qbase + 64 + lg*16);

  // drain pre-loop VMEM/LDS so in-loop vmcnt counts ONLY stage loads
  asm volatile("s_waitcnt vmcnt(0) lgkmcnt(0)" ::: "memory");

  f32x4 oacc[4];
  #pragma unroll
  for (int i = 0; i < 4; i++) oacc[i] = f32x4{0.f,0.f,0.f,0.f};
  float den[4] = {0.f, 0.f, 0.f, 0.f};

  const uint8_t* kgb = (const uint8_t*)Kd + (size_t)b*SS*128;
  const uint8_t* vgb = (const uint8_t*)Vt + (size_t)b*DOUT*SS*2;
  uint8_t* pbase = smem + 98304 + w*4096;

  auto STAGE = [&](int kb, int bi) {  // 8 gl_lds per wave
    uint8_t* bk_ = smem + bi*32768;
    uint8_t* bv_ = bk_ + 16384;
    #pragma unroll
    for (int j = 0; j < 4; j++) {     // K chunk: 128 rows x 128B
      int g = j*256 + w*64 + lane;
      int key = g >> 3, u1 = g & 7;
      int u = u1 ^ (key & 7);
      gl_lds16(kgb + (size_t)(kb*128 + key)*128 + u*16, bk_ + (j*256 + w*64)*16);
    }
    #pragma unroll
    for (int j = 0; j < 4; j++) {     // V chunk: 64 rows x 256B
      int g = j*256 + w*64 + lane;
      int d = g >> 4, u1 = g & 15;
      int u = u1 ^ (d & 15);
      gl_lds16(vgb + (size_t)d*4096 + kb*256 + u*16, bv_ + (j*256 + w*64)*16);
    }
  };

  STAGE(0, 0);
  STAGE(1, 1);
  for (int kb = 0; kb < 16; kb++) {
    if (kb < 15) asm volatile("s_waitcnt vmcnt(8)" ::: "memory");
    else         asm volatile("s_waitcnt vmcnt(0)" ::: "memory");
    __builtin_amdgcn_s_barrier();
    __builtin_amdgcn_sched_barrier(0);
    if (kb + 2 < 16) STAGE(kb + 2, (kb + 2) % 3);

    uint8_t* bk_ = smem + (kb % 3)*32768;
    uint8_t* bv_ = bk_ + 16384;
    // QK^T
    f32x4 sacc[8];
    #pragma unroll
    for (int i = 0; i < 8; i++) sacc[i] = f32x4{0.f,0.f,0.f,0.f};
    #pragma unroll
    for (int kk = 0; kk < 2; kk++) {
      #pragma unroll
      for (int nf = 0; nf < 8; nf++) {
        int key = nf*16 + ll;
        short8 kf = *(const short8*)(bk_ + key*128 + (((kk*4 + lg) ^ (key & 7))*16));
        sacc[nf] = __builtin_amdgcn_mfma_f32_16x16x32_bf16(aq[kk], kf, sacc[nf], 0, 0, 0);
      }
    }
    // p = mask * exp(s); bf16 P -> per-wave LDS; accumulate denominator
    #pragma unroll
    for (int nf = 0; nf < 8; nf++) {
      float msk = fml[kb*128 + nf*16 + ll];
      #pragma unroll
      for (int r = 0; r < 4; r++) {
        float p = msk * __expf(sacc[nf][r]);
        __bf16 pb = (__bf16)p;
        den[r] += (float)pb;
        int qrow = lg*4 + r;
        int col = nf*16 + ll;
        *(__bf16*)(pbase + qrow*256 + (((col >> 3) ^ qrow)*16) + (col & 7)*2) = pb;
      }
    }
    // PV (per-wave-private P: in-wave lgkm ordering by compiler)
    #pragma unroll
    for (int ks = 0; ks < 4; ks++) {
      int u = ks*4 + lg;
      short8 pf = *(const short8*)(pbase + ll*256 + ((u ^ ll)*16));
      #pragma unroll
      for (int df = 0; df < 4; df++) {
        int d = df*16 + ll;
        short8 vf = *(const short8*)(bv_ + d*256 + ((u ^ (d & 15))*16));
        oacc[df] = __builtin_amdgcn_mfma_f32_16x16x32_bf16(pf, vf, oacc[df], 0, 0, 0);
      }
    }
  }
  // denominator: reduce across the 16 lanes sharing each C-fragment row group
  #pragma unroll
  for (int r = 0; r < 4; r++) {
    float d = den[r];
    d += __shfl_xor(d, 1, 64);
    d += __shfl_xor(d, 2, 64);
    d += __shfl_xor(d, 4, 64);
    d += __shfl_xor(d, 8, 64);
    den[r] = d;
  }
  #pragma unroll
  for (int df = 0; df < 4; df++) {
    int col = df*16 + ll;
    #pragma unroll
    for (int r = 0; r < 4; r++) {
      int gq = b*SS + q0 + lg*4 + r;
      out[(size_t)gq*DOUT + col] = oacc[df][r] / den[r];
    }
  }
}

extern "C" void kernel_launch(void* const* d_in, const int* in_sizes, int n_in,
                              void* d_out, int out_size, void* d_ws, size_t ws_size,
                              hipStream_t stream) {
  const float* seq = (const float*)d_in[0];
  const void*  msk = d_in[1];
  const float* Wq  = (const float*)d_in[2];
  const float* bq  = (const float*)d_in[3];
  const float* Wk  = (const float*)d_in[4];
  const float* bk  = (const float*)d_in[5];
  const float* Wv  = (const float*)d_in[6];
  const float* bv  = (const float*)d_in[7];
  uint8_t* ws = (uint8_t*)d_ws;
  __bf16* Wt  = (__bf16*)(ws + WT_OFF);
  float*  fm  = (float*)(ws + FM_OFF);
  __bf16* Qb  = (__bf16*)(ws + Q_OFF);
  __bf16* Kb  = (__bf16*)(ws + K_OFF);
  __bf16* Vtb = (__bf16*)(ws + VT_OFF);
  float* out  = (float*)d_out;

  k_prep<<<dim3(112), dim3(256), 0, stream>>>(Wq, Wk, Wv, msk, Wt, fm);
  k_qkv<<<dim3(256), dim3(256), 0, stream>>>(seq, Wt, bq, bk, bv, Qb, Kb, Vtb);
  k_attn<<<dim3(256), dim3(256), 0, stream>>>(Qb, Kb, Vtb, fm, out);
}